// Round 19
// baseline (202.510 us; speedup 1.0000x reference)
//
#include <hip/hip_runtime.h>
#include <hip/hip_bf16.h>
#include <cstdint>

typedef __hip_bfloat16 bf16;
typedef __attribute__((ext_vector_type(8))) short short8;
typedef __attribute__((ext_vector_type(4))) short short4v;
typedef __attribute__((ext_vector_type(4))) float f32x4;

#define T_   2048
#define CDIM 2048
#define NH   16
#define NKV  4
#define HD   128
// 1/sqrt(128) * log2(e), folded into q at the fused epilogue (exp2-domain scores)
#define QSCALE (0.08838834764831845f * 1.44269504088896340f)

__device__ __forceinline__ void gload_lds16(const void* g, void* l) {
  __builtin_amdgcn_global_load_lds(
      (const __attribute__((address_space(1))) void*)g,
      (__attribute__((address_space(3))) void*)l, 16, 0, 0);
}

template <int G> __device__ __forceinline__ void vm_gate() {
  if constexpr (G == 5)      asm volatile("s_waitcnt vmcnt(5)" ::: "memory");
  else if constexpr (G == 4) asm volatile("s_waitcnt vmcnt(4)" ::: "memory");
  else if constexpr (G == 3) asm volatile("s_waitcnt vmcnt(3)" ::: "memory");
  else                       asm volatile("s_waitcnt vmcnt(0)" ::: "memory");
}

// ---------------- fused preamble: cast x + cast/transpose all W + gate vector -------
// [0,8192): x fp32->bf16. [8192,12288): Wq^T. [12288,13312): Wk^T.
// [13312,14336): Wv^T. [14336,18432): Wo^T. [18432,20480): gate4[4096][4]
// (2 rows/block: gate = 2*sigmoid(x[:, :32] @ Wg), consumed by the fused QKV epilogue).
__global__ __launch_bounds__(256) void prep_kernel(
    const float* __restrict__ x, const float* __restrict__ Wq,
    const float* __restrict__ Wk, const float* __restrict__ Wv,
    const float* __restrict__ Wo, const float* __restrict__ Wg,
    ushort4* __restrict__ xb, bf16* __restrict__ wT, bf16* __restrict__ woT,
    float* __restrict__ gate4) {
  int b = blockIdx.x;
  if (b < 8192) {
    int i = b * 256 + threadIdx.x;
    float4 v = ((const float4*)x)[i];
    union { bf16 h[4]; ushort4 u; } cv;
    cv.h[0] = __float2bfloat16(v.x);
    cv.h[1] = __float2bfloat16(v.y);
    cv.h[2] = __float2bfloat16(v.z);
    cv.h[3] = __float2bfloat16(v.w);
    xb[i] = cv.u;
    return;
  }
  if (b >= 18432) {
    int idx = b - 18432;
    int row = idx * 2 + (threadIdx.x >> 7);
    int tt = threadIdx.x & 127;
    int g = tt >> 5, i = tt & 31;
    float p = x[(size_t)row * CDIM + i] * Wg[i * 4 + g];
    p += __shfl_xor(p, 1);  p += __shfl_xor(p, 2);
    p += __shfl_xor(p, 4);  p += __shfl_xor(p, 8);
    p += __shfl_xor(p, 16);
    if (i == 0) gate4[row * 4 + g] = 2.f / (1.f + __expf(-p));
    return;
  }
  const float* W; bf16* WT; int N, nbx, idx;
  if (b < 12288)      { W = Wq; WT = wT;                       N = 2048; nbx = 64; idx = b - 8192; }
  else if (b < 13312) { W = Wk; WT = wT + (size_t)2048 * 2048; N = 512;  nbx = 16; idx = b - 12288; }
  else if (b < 14336) { W = Wv; WT = wT + (size_t)2560 * 2048; N = 512;  nbx = 16; idx = b - 13312; }
  else                { W = Wo; WT = woT;                      N = 2048; nbx = 64; idx = b - 14336; }
  __shared__ float tile[32][33];
  const int K = 2048;
  int n0 = (idx % nbx) * 32, k0 = (idx / nbx) * 32;
  int r = threadIdx.x >> 5, c = threadIdx.x & 31;
  for (int i = 0; i < 4; ++i)
    tile[r + i * 8][c] = W[(size_t)(k0 + r + i * 8) * N + n0 + c];
  __syncthreads();
  for (int i = 0; i < 4; ++i)
    WT[(size_t)(n0 + r + i * 8) * K + k0 + c] = __float2bfloat16(tile[c][r + i * 8]);
}

// ---------------- fused QKV GEMM + epilogue (BN=128 = exactly one head) ------------
// GEMM: r13/r17 quadrant schedule, MH=4/NF=2 (BM=128, BN=128, BK=64), 8 waves 2Mx4N,
// LDS 64KB -> 2 blocks/CU; grid 32x24 = 768. After the K-loop the 128x128 fp32 acc
// is spilled to LDS (reusing the staging space), then each wave epilogues one
// token-row at a time: RoPE pair (d, d+64) = (lane, lane+64), RMSNorm = within-wave
// shuffle reduce; bx<16 -> q head (QSCALE folded), bx<20 -> k head, else v head
// (gate4 + ve add, transposed store). Deletes the epilogue kernel + 50MB qkv traffic.
__global__ __launch_bounds__(512, 2) void gemm_qkvf(
    const bf16* __restrict__ A, const bf16* __restrict__ BT,
    const float* __restrict__ ve, const float* __restrict__ cosT,
    const float* __restrict__ sinT, const float* __restrict__ gate4,
    bf16* __restrict__ qn, bf16* __restrict__ kn, bf16* __restrict__ vT) {
  __shared__ __align__(16) char smem[65536];
  const int K = 2048;

  int tid = threadIdx.x;
  int lane = tid & 63, w = tid >> 6;
  int wm = w >> 2, wn = w & 3;
  int lr = lane & 15, lk = lane >> 4;

  int xcd = blockIdx.x & 7, t = blockIdx.x >> 3;   // regions 8x12 in 4x2 layout
  int by = (xcd >> 1) * 8 + t / 12;
  int bx = (xcd & 1) * 12 + t % 12;
  int m0 = by * 128, n0 = bx * 128;

  f32x4 acc[4][2];
#pragma unroll
  for (int m = 0; m < 4; ++m)
#pragma unroll
    for (int n = 0; n < 2; ++n) acc[m][n] = (f32x4){0.f, 0.f, 0.f, 0.f};

  const bf16* Abase = A + (size_t)m0 * K;
  const bf16* Bbase = BT + (size_t)n0 * K;

  auto sAp = [&](int p) { return smem + p * 16384; };
  auto sBp = [&](int p) { return smem + 32768 + p * 16384; };

  auto stB = [&](int p, int kt) {
    int kb = kt << 6;
#pragma unroll
    for (int i = 0; i < 2; ++i) {
      int c = i * 512 + tid;
      int r = c >> 3, sl = c & 7;
      gload_lds16(Bbase + (size_t)r * K + kb + ((sl ^ (r & 7)) << 3),
                  sBp(p) + c * 16);
    }
  };
  auto stA = [&](int p, int kt, int h) {
    int kb = kt << 6;
    int c = tid;
    int r = (c >> 3) + h * 64, sl = c & 7;
    gload_lds16(Abase + (size_t)r * K + kb + ((sl ^ (r & 7)) << 3),
                sAp(p) + r * 128 + sl * 16);
  };

  int nk = K >> 6;
  stB(0, 0); stA(0, 0, 0); stA(0, 0, 1);
  stB(1, 1); stA(1, 1, 0);
  vm_gate<3>();
  __builtin_amdgcn_s_barrier();

#define READ_AF(DST, QM)                                                   \
  {                                                                        \
    _Pragma("unroll")                                                      \
    for (int mi = 0; mi < 2; ++mi) {                                       \
      int row = wm * 64 + (QM) * 32 + mi * 16 + lr;                        \
      const char* rb = sAb + row * 128;                                    \
      int rx = (row & 7) << 4;                                             \
      DST[mi][0] = *(const short8*)(rb + ((lk * 16) ^ rx));                \
      DST[mi][1] = *(const short8*)(rb + ((64 + lk * 16) ^ rx));           \
    }                                                                      \
  }
#define READ_BF(DST, FB)                                                   \
  {                                                                        \
    int row = wn * 32 + (FB) * 16 + lr;                                    \
    const char* rb = sBb + row * 128;                                      \
    int rx = (row & 7) << 4;                                               \
    DST[0][0] = *(const short8*)(rb + ((lk * 16) ^ rx));                   \
    DST[0][1] = *(const short8*)(rb + ((64 + lk * 16) ^ rx));              \
  }
#define MFMA_Q(AF, BF, QM, FB)                                             \
  __builtin_amdgcn_s_setprio(1);                                           \
  _Pragma("unroll")                                                        \
  for (int kk = 0; kk < 2; ++kk)                                           \
    _Pragma("unroll")                                                      \
    for (int mi = 0; mi < 2; ++mi)                                         \
      acc[(QM) * 2 + mi][FB] = __builtin_amdgcn_mfma_f32_16x16x32_bf16(    \
          AF[mi][kk], BF[0][kk], acc[(QM) * 2 + mi][FB], 0, 0, 0);         \
  __builtin_amdgcn_s_setprio(0);
#define RD_SYNC                                                            \
  __builtin_amdgcn_s_barrier();                                            \
  asm volatile("s_waitcnt lgkmcnt(0)" ::: "memory");                       \
  __builtin_amdgcn_sched_barrier(0);

  for (int kt = 0; kt < nk; ++kt) {
    int p = kt & 1;
    const char* sAb = (const char*)sAp(p);
    const char* sBb = (const char*)sBp(p);
    short8 af0[2][2], af1[2][2], bf0[1][2], bf1[1][2];

    READ_AF(af0, 0);
    READ_BF(bf0, 0);
    if (kt + 1 < nk) stA(p ^ 1, kt + 1, 1);
    RD_SYNC;
    MFMA_Q(af0, bf0, 0, 0);
    __builtin_amdgcn_s_barrier();

    READ_BF(bf1, 1);
    RD_SYNC;
    MFMA_Q(af0, bf1, 0, 1);
    __builtin_amdgcn_s_barrier();

    READ_AF(af1, 1);
    if (kt + 2 < nk) stB(p, kt + 2);
    RD_SYNC;
    MFMA_Q(af1, bf1, 1, 1);
    __builtin_amdgcn_s_barrier();

    if (kt + 2 < nk) stA(p, kt + 2, 0);
    MFMA_Q(af1, bf0, 1, 0);
    if (kt + 2 < nk) vm_gate<3>();
    else             vm_gate<0>();
    __builtin_amdgcn_s_barrier();
  }
#undef READ_AF
#undef READ_BF
#undef MFMA_Q
#undef RD_SYNC

  // ---- spill acc to LDS fp32 [128][128] (staging buffers dead) ----
  float* tl = (float*)smem;
#pragma unroll
  for (int m = 0; m < 4; ++m)
#pragma unroll
    for (int n = 0; n < 2; ++n)
#pragma unroll
      for (int jj = 0; jj < 4; ++jj) {
        int row = wm * 64 + (m >> 1) * 32 + (m & 1) * 16 + lk * 4 + jj;
        int col = wn * 32 + n * 16 + lr;
        tl[row * 128 + col] = acc[m][n][jj];
      }
  __syncthreads();

  // ---- fused epilogue: one wave per token-row, 16 iterations of 8 rows ----
  if (bx < 16) {                       // q head: rope + rmsnorm, QSCALE folded
    size_t hb = (size_t)bx * 128;
    for (int it = 0; it < 16; ++it) {
      int row = it * 8 + w;
      int grow = m0 + row;
      int tk = grow & (T_ - 1);
      float x1 = tl[row * 128 + lane];
      float x2 = tl[row * 128 + 64 + lane];
      float cv = cosT[tk * 64 + lane], sv = sinT[tk * 64 + lane];
      float y1 = x1 * cv + x2 * sv;
      float y2 = x2 * cv - x1 * sv;
      float ss = y1 * y1 + y2 * y2;
      ss += __shfl_xor(ss, 1);  ss += __shfl_xor(ss, 2);  ss += __shfl_xor(ss, 4);
      ss += __shfl_xor(ss, 8);  ss += __shfl_xor(ss, 16); ss += __shfl_xor(ss, 32);
      float r = rsqrtf(ss * (1.f / 128.f) + 1e-6f) * QSCALE;
      qn[(size_t)grow * (NH * HD) + hb + lane]      = __float2bfloat16(y1 * r);
      qn[(size_t)grow * (NH * HD) + hb + 64 + lane] = __float2bfloat16(y2 * r);
    }
  } else if (bx < 20) {                // k head: rope + rmsnorm
    size_t hb = (size_t)(bx - 16) * 128;
    for (int it = 0; it < 16; ++it) {
      int row = it * 8 + w;
      int grow = m0 + row;
      int tk = grow & (T_ - 1);
      float x1 = tl[row * 128 + lane];
      float x2 = tl[row * 128 + 64 + lane];
      float cv = cosT[tk * 64 + lane], sv = sinT[tk * 64 + lane];
      float y1 = x1 * cv + x2 * sv;
      float y2 = x2 * cv - x1 * sv;
      float ss = y1 * y1 + y2 * y2;
      ss += __shfl_xor(ss, 1);  ss += __shfl_xor(ss, 2);  ss += __shfl_xor(ss, 4);
      ss += __shfl_xor(ss, 8);  ss += __shfl_xor(ss, 16); ss += __shfl_xor(ss, 32);
      float r = rsqrtf(ss * (1.f / 128.f) + 1e-6f);
      kn[(size_t)grow * (NKV * HD) + hb + lane]      = __float2bfloat16(y1 * r);
      kn[(size_t)grow * (NKV * HD) + hb + 64 + lane] = __float2bfloat16(y2 * r);
    }
  } else {                             // v head: gate*ve add, transposed store
    int kv = bx - 20;
    for (int it = 0; it < 16; ++it) {
      int row = it * 8 + w;
      int grow = m0 + row;
      int tk = grow & (T_ - 1);
      int bi = grow >> 11;
      float g = gate4[grow * 4 + kv];
      const float* vep = ve + (size_t)grow * (NKV * HD) + kv * 128;
      float v1 = tl[row * 128 + lane]      + g * vep[lane];
      float v2 = tl[row * 128 + 64 + lane] + g * vep[64 + lane];
      size_t vb = (size_t)(bi * NKV + kv) * 128;
      vT[(vb + lane) * T_ + tk]      = __float2bfloat16(v1);
      vT[(vb + 64 + lane) * T_ + tk] = __float2bfloat16(v2);
    }
  }
}

// ---------------- quadrant-phase GEMM (r17/r18 proven), used for Wo ----------------
template <int MH, int NF, typename CT>
__global__ __launch_bounds__(512, 2) void gemm_q4(const bf16* __restrict__ A,
                                                  const bf16* __restrict__ BT,
                                                  CT* __restrict__ C,
                                                  int N, int K, int RY, int RX) {
  constexpr int BM = MH * 32;
  constexpr int BN = NF * 64;
  constexpr int MQ = MH / 2;
  constexpr int ALOADS = (MH + 3) / 4;
  constexpr int NB0 = (NF + 1) / 2;
  constexpr int NB1 = NF - NB0;
  constexpr int GATE = NF + ALOADS;
  __shared__ __align__(16) bf16 sA[2][BM * 64];
  __shared__ __align__(16) bf16 sB[2][BN * 64];

  int tid = threadIdx.x;
  int lane = tid & 63, w = tid >> 6;
  int wm = w >> 2, wn = w & 3;
  int lr = lane & 15, lk = lane >> 4;

  int xcd = blockIdx.x & 7, t = blockIdx.x >> 3;
  int by = (xcd >> 1) * RY + t / RX;
  int bx = (xcd & 1) * RX + t % RX;
  int m0 = by * BM, n0 = bx * BN;

  f32x4 acc[MH][NF];
#pragma unroll
  for (int m = 0; m < MH; ++m)
#pragma unroll
    for (int n = 0; n < NF; ++n) acc[m][n] = (f32x4){0.f, 0.f, 0.f, 0.f};

  const bf16* Abase = A + (size_t)m0 * K;
  const bf16* Bbase = BT + (size_t)n0 * K;

  auto stB = [&](int p, int kt) {
    int kb = kt << 6;
#pragma unroll
    for (int i = 0; i < NF; ++i) {
      int c = i * 512 + tid;
      int r = c >> 3, sl = c & 7;
      gload_lds16(Bbase + (size_t)r * K + kb + ((sl ^ (r & 7)) << 3),
                  (char*)(&sB[p][0]) + c * 16);
    }
  };
  auto stA = [&](int p, int kt, int h) {
    int kb = kt << 6;
#pragma unroll
    for (int i = 0; i < ALOADS; ++i) {
      int c = i * 512 + tid;
      int r = (c >> 3) + h * (BM / 2), sl = c & 7;
      gload_lds16(Abase + (size_t)r * K + kb + ((sl ^ (r & 7)) << 3),
                  (char*)(&sA[p][0]) + r * 128 + sl * 16);
    }
  };

  int nk = K >> 6;
  stB(0, 0); stA(0, 0, 0); stA(0, 0, 1);
  stB(1, 1); stA(1, 1, 0);
  vm_gate<GATE>();
  __builtin_amdgcn_s_barrier();

#define READ_AF(DST, QM)                                                   \
  {                                                                        \
    _Pragma("unroll")                                                      \
    for (int mi = 0; mi < MQ; ++mi) {                                      \
      int row = wm * (MH * 16) + (QM) * (MQ * 16) + mi * 16 + lr;          \
      const char* rb = sAb + row * 128;                                    \
      int rx = (row & 7) << 4;                                             \
      DST[mi][0] = *(const short8*)(rb + ((lk * 16) ^ rx));                \
      DST[mi][1] = *(const short8*)(rb + ((64 + lk * 16) ^ rx));           \
    }                                                                      \
  }
#define READ_BF(DST, FBASE, CNT)                                           \
  {                                                                        \
    _Pragma("unroll")                                                      \
    for (int f = 0; f < (CNT); ++f) {                                      \
      int row = wn * (NF * 16) + ((FBASE) + f) * 16 + lr;                  \
      const char* rb = sBb + row * 128;                                    \
      int rx = (row & 7) << 4;                                             \
      DST[f][0] = *(const short8*)(rb + ((lk * 16) ^ rx));                 \
      DST[f][1] = *(const short8*)(rb + ((64 + lk * 16) ^ rx));            \
    }                                                                      \
  }
#define MFMA_Q(AF, BF, QM, FBASE, CNT)                                     \
  __builtin_amdgcn_s_setprio(1);                                           \
  _Pragma("unroll")                                                        \
  for (int kk = 0; kk < 2; ++kk)                                           \
    _Pragma("unroll")                                                      \
    for (int mi = 0; mi < MQ; ++mi)                                        \
      _Pragma("unroll")                                                    \
      for (int f = 0; f < (CNT); ++f)                                      \
        acc[(QM) * MQ + mi][(FBASE) + f] =                                 \
            __builtin_amdgcn_mfma_f32_16x16x32_bf16(                       \
                AF[mi][kk], BF[f][kk], acc[(QM) * MQ + mi][(FBASE) + f],   \
                0, 0, 0);                                                  \
  __builtin_amdgcn_s_setprio(0);
#define RD_SYNC                                                            \
  __builtin_amdgcn_s_barrier();                                            \
  asm volatile("s_waitcnt lgkmcnt(0)" ::: "memory");                       \
  __builtin_amdgcn_sched_barrier(0);

  for (int kt = 0; kt < nk; ++kt) {
    int p = kt & 1;
    const char* sAb = (const char*)(&sA[p][0]);
    const char* sBb = (const char*)(&sB[p][0]);
    short8 af0[MQ][2], af1[MQ][2], bf0[NB0][2], bf1[NB1][2];

    READ_AF(af0, 0);
    READ_BF(bf0, 0, NB0);
    if (kt + 1 < nk) stA(p ^ 1, kt + 1, 1);
    RD_SYNC;
    MFMA_Q(af0, bf0, 0, 0, NB0);
    __builtin_amdgcn_s_barrier();

    READ_BF(bf1, NB0, NB1);
    RD_SYNC;
    MFMA_Q(af0, bf1, 0, NB0, NB1);
    __builtin_amdgcn_s_barrier();

    READ_AF(af1, 1);
    if (kt + 2 < nk) stB(p, kt + 2);
    RD_SYNC;
    MFMA_Q(af1, bf1, 1, NB0, NB1);
    __builtin_amdgcn_s_barrier();

    if (kt + 2 < nk) stA(p, kt + 2, 0);
    MFMA_Q(af1, bf0, 1, 0, NB0);
    if (kt + 2 < nk) vm_gate<GATE>();
    else             vm_gate<0>();
    __builtin_amdgcn_s_barrier();
  }
#undef READ_AF
#undef READ_BF
#undef MFMA_Q
#undef RD_SYNC

#pragma unroll
  for (int m = 0; m < MH; ++m)
#pragma unroll
    for (int n = 0; n < NF; ++n)
#pragma unroll
      for (int jj = 0; jj < 4; ++jj) {
        size_t idx = (size_t)(m0 + wm * (MH * 16) + (m / MQ) * (MQ * 16) +
                              (m % MQ) * 16 + lk * 4 + jj) * N +
                     n0 + wn * (NF * 16) + n * 16 + lr;
        if constexpr (__is_same(CT, float))
          C[idx] = acc[m][n][jj];
        else
          C[idx] = __float2bfloat16(acc[m][n][jj]);
      }
}

// ---------------- flash attention v7: QBLK=128, double-buffered LDS, 1 barrier/tile --
__global__ __launch_bounds__(256, 2) void attn_kernel(
    const bf16* __restrict__ qn, const bf16* __restrict__ kn,
    const bf16* __restrict__ vT, bf16* __restrict__ y,
    const int* __restrict__ winp) {
  __shared__ __align__(16) bf16 sK[2][64 * 128];
  __shared__ __align__(16) bf16 sV[2][128 * 64];

  int win = *winp;
  int id = blockIdx.x;
  int g  = id & 7;
  int bi = g >> 2, kvh = g & 3;
  int rem = id >> 3;
  int h  = kvh * 4 + (rem & 3);
  int q0 = (rem >> 2) << 7;
  int tid = threadIdx.x;
  int lane = tid & 63, w = tid >> 6;
  int lr = lane & 15, lk = lane >> 4;

  short8 qfA[4], qfB[4];
  {
    const bf16* qrA = qn + (size_t)(bi * T_ + q0 + w * 32 + lr) * (NH * HD) + h * HD;
    const bf16* qrB = qrA + (size_t)16 * (NH * HD);
#pragma unroll
    for (int c = 0; c < 4; ++c) {
      qfA[c] = *(const short8*)(qrA + c * 32 + lk * 8);
      qfB[c] = *(const short8*)(qrB + c * 32 + lk * 8);
    }
  }

  int kge[4], klb[4], vge[4], vlbA[4], vlbB[4];
#pragma unroll
  for (int i = 0; i < 4; ++i) {
    int c = i * 256 + tid;
    int kr = c >> 4, ks = c & 15;
    kge[i] = kr * (NKV * HD) + ks * 8;
    klb[i] = kr * 256 + ((ks ^ (kr & 7)) << 4);
    int vr = c >> 3, vs = c & 7;
    vge[i] = vr * T_ + vs * 8;
    int hh = vs >> 2, m = vs & 3, a = m >> 1;
    int sA = 8 * ((2 * m) & 3) + 4 * a;
    int sB = 8 * ((2 * m + 1) & 3) + 4 * a;
    int tA = 64 * hh + 2 * sA, tB = 64 * hh + 2 * sB;
    vlbA[i] = vr * 128 + (((tA >> 4) ^ (vr & 7)) << 4) + (tA & 15);
    vlbB[i] = vr * 128 + (((tB >> 4) ^ (vr & 7)) << 4) + (tB & 15);
  }
  const bf16* kpane = kn + (size_t)bi * T_ * (NKV * HD) + kvh * HD;
  const bf16* vpane = vT + (size_t)(bi * NKV + kvh) * HD * T_;

  short8 kreg[4], vreg[4];
  auto LOAD = [&](int jtx) {
    const bf16* kb = kpane + (size_t)(jtx << 6) * (NKV * HD);
    const bf16* vb = vpane + (jtx << 6);
#pragma unroll
    for (int i = 0; i < 4; ++i) kreg[i] = *(const short8*)(kb + kge[i]);
#pragma unroll
    for (int i = 0; i < 4; ++i) vreg[i] = *(const short8*)(vb + vge[i]);
  };
  auto WRITE = [&](int b) {
    char* kBuf = (char*)(&sK[b][0]);
    char* vBuf = (char*)(&sV[b][0]);
#pragma unroll
    for (int i = 0; i < 4; ++i) *(short8*)(kBuf + klb[i]) = kreg[i];
#pragma unroll
    for (int i = 0; i < 4; ++i) {
      union { short8 s8; short4v s4[2]; } u;
      u.s8 = vreg[i];
      *(short4v*)(vBuf + vlbA[i]) = u.s4[0];
      *(short4v*)(vBuf + vlbB[i]) = u.s4[1];
    }
  };

  f32x4 o0[8], o1[8];
#pragma unroll
  for (int i = 0; i < 8; ++i) {
    o0[i] = (f32x4){0.f, 0.f, 0.f, 0.f};
    o1[i] = (f32x4){0.f, 0.f, 0.f, 0.f};
  }
  float lp0 = 0.f, lp1 = 0.f;

  int jt0 = q0 >> 6;
  int hi = q0 + 126 + win; if (hi > T_ - 1) hi = T_ - 1;
  int jt1 = hi >> 6;

  LOAD(jt0);
  WRITE(0);
  if (jt0 < jt1) LOAD(jt0 + 1);
  asm volatile("s_waitcnt lgkmcnt(0)\n\ts_barrier" ::: "memory");

  int irow0 = q0 + w * 32 + lr;
  int klo = lk * 4;

  int p = 0;
  for (int jt = jt0; jt <= jt1; ++jt) {
    int j0 = jt << 6;

    if (jt < jt1) {
      WRITE(p ^ 1);
      if (jt + 1 < jt1) LOAD(jt + 2);
    }

    const char* sKb = (const char*)(&sK[p][0]);
    const char* sVb = (const char*)(&sV[p][0]);

    f32x4 s0[4], s1[4];
#pragma unroll
    for (int sub = 0; sub < 4; ++sub) {
      s0[sub] = (f32x4){0.f, 0.f, 0.f, 0.f};
      s1[sub] = (f32x4){0.f, 0.f, 0.f, 0.f};
    }
    __builtin_amdgcn_s_setprio(1);
#pragma unroll
    for (int sub = 0; sub < 4; ++sub) {
      int kr = sub * 16 + lr;
      int rx = (kr & 7) << 4;
      const char* rowb = sKb + kr * 256;
#pragma unroll
      for (int c = 0; c < 4; ++c) {
        short8 kf = *(const short8*)(rowb + ((c * 64 + lk * 16) ^ rx));
        s0[sub] = __builtin_amdgcn_mfma_f32_16x16x32_bf16(kf, qfA[c], s0[sub], 0, 0, 0);
        s1[sub] = __builtin_amdgcn_mfma_f32_16x16x32_bf16(kf, qfB[c], s1[sub], 0, 0, 0);
      }
    }
    __builtin_amdgcn_s_setprio(0);

    bool full = (j0 >= q0 + 128) && (j0 + 64 <= q0 + win);
    int koff0 = j0 - irow0;
    int koff1 = koff0 - 16;

    short8 pA0, pA1, pB0, pB1;
    {
      unsigned pk[8];
#pragma unroll
      for (int sub = 0; sub < 4; ++sub) {
        float p0 = exp2f(s0[sub][0]), p1 = exp2f(s0[sub][1]);
        float p2 = exp2f(s0[sub][2]), p3 = exp2f(s0[sub][3]);
        if (!full) {
          int base = koff0 + sub * 16 + klo;
          p0 = ((unsigned)(base + 0) < (unsigned)win) ? p0 : 0.f;
          p1 = ((unsigned)(base + 1) < (unsigned)win) ? p1 : 0.f;
          p2 = ((unsigned)(base + 2) < (unsigned)win) ? p2 : 0.f;
          p3 = ((unsigned)(base + 3) < (unsigned)win) ? p3 : 0.f;
        }
        lp0 += (p0 + p1) + (p2 + p3);
        asm("v_cvt_pk_bf16_f32 %0, %1, %2" : "=v"(pk[sub * 2])     : "v"(p0), "v"(p1));
        asm("v_cvt_pk_bf16_f32 %0, %1, %2" : "=v"(pk[sub * 2 + 1]) : "v"(p2), "v"(p3));
      }
      union { unsigned u[4]; short8 s8; } c0, c1;
      c0.u[0] = pk[0]; c0.u[1] = pk[1]; c0.u[2] = pk[2]; c0.u[3] = pk[3];
      c1.u[0] = pk[4]; c1.u[1] = pk[5]; c1.u[2] = pk[6]; c1.u[3] = pk[7];
      pA0 = c0.s8; pA1 = c1.s8;
    }
    {
      unsigned pk[8];
#pragma unroll
      for (int sub = 0; sub < 4; ++sub) {
        float p0 = exp2f(s1[sub][0]), p1 = exp2f(s1[sub][1]);
        float p2 = exp2f(s1[sub][2]), p3 = exp2f(s1[sub][3]);
        if (!full) {
          int base = koff1 + sub * 16 + klo;
          p0 = ((unsigned)(base + 0) < (unsigned)win) ? p0 : 0.f;
          p1 = ((unsigned)(base + 1) < (unsigned)win) ? p1 : 0.f;
          p2 = ((unsigned)(base + 2) < (unsigned)win) ? p2 : 0.f;
          p3 = ((unsigned)(base + 3) < (unsigned)win) ? p3 : 0.f;
        }
        lp1 += (p0 + p1) + (p2 + p3);
        asm("v_cvt_pk_bf16_f32 %0, %1, %2" : "=v"(pk[sub * 2])     : "v"(p0), "v"(p1));
        asm("v_cvt_pk_bf16_f32 %0, %1, %2" : "=v"(pk[sub * 2 + 1]) : "v"(p2), "v"(p3));
      }
      union { unsigned u[4]; short8 s8; } c0, c1;
      c0.u[0] = pk[0]; c0.u[1] = pk[1]; c0.u[2] = pk[2]; c0.u[3] = pk[3];
      c1.u[0] = pk[4]; c1.u[1] = pk[5]; c1.u[2] = pk[6]; c1.u[3] = pk[7];
      pB0 = c0.s8; pB1 = c1.s8;
    }

    __builtin_amdgcn_s_setprio(1);
#pragma unroll
    for (int nb = 0; nb < 8; ++nb) {
      int vr = nb * 16 + lr;
      int vrx = (vr & 7) << 4;
      const char* vb = sVb + vr * 128;
      short8 vf0 = *(const short8*)(vb + ((lk * 16) ^ vrx));
      short8 vf1 = *(const short8*)(vb + ((64 + lk * 16) ^ vrx));
      o0[nb] = __builtin_amdgcn_mfma_f32_16x16x32_bf16(pA0, vf0, o0[nb], 0, 0, 0);
      o0[nb] = __builtin_amdgcn_mfma_f32_16x16x32_bf16(pA1, vf1, o0[nb], 0, 0, 0);
      o1[nb] = __builtin_amdgcn_mfma_f32_16x16x32_bf16(pB0, vf0, o1[nb], 0, 0, 0);
      o1[nb] = __builtin_amdgcn_mfma_f32_16x16x32_bf16(pB1, vf1, o1[nb], 0, 0, 0);
    }
    __builtin_amdgcn_s_setprio(0);

    asm volatile("s_waitcnt lgkmcnt(0)\n\ts_barrier" ::: "memory");
    p ^= 1;
  }

  float l0 = lp0, l1 = lp1;
  l0 += __shfl_xor(l0, 16); l0 += __shfl_xor(l0, 32);
  l1 += __shfl_xor(l1, 16); l1 += __shfl_xor(l1, 32);
#pragma unroll
  for (int jj = 0; jj < 4; ++jj) {
    float inv0 = 1.f / __shfl(l0, klo + jj);
    float inv1 = 1.f / __shfl(l1, klo + jj);
    size_t ob0 = (size_t)(bi * T_ + q0 + w * 32 + klo + jj) * (NH * HD) + h * HD;
    size_t ob1 = ob0 + (size_t)16 * (NH * HD);
#pragma unroll
    for (int nb = 0; nb < 8; ++nb) {
      y[ob0 + nb * 16 + lr] = __float2bfloat16(o0[nb][jj] * inv0);
      y[ob1 + nb * 16 + lr] = __float2bfloat16(o1[nb][jj] * inv1);
    }
  }
}

extern "C" void kernel_launch(void* const* d_in, const int* in_sizes, int n_in,
                              void* d_out, int out_size, void* d_ws, size_t ws_size,
                              hipStream_t stream) {
  const float* x    = (const float*)d_in[0];
  const float* ve   = (const float*)d_in[1];
  const float* cosT = (const float*)d_in[2];
  const float* sinT = (const float*)d_in[3];
  const float* Wq   = (const float*)d_in[4];
  const float* Wk   = (const float*)d_in[5];
  const float* Wv   = (const float*)d_in[6];
  const float* Wg   = (const float*)d_in[7];
  const float* Wo   = (const float*)d_in[8];
  const int*   win  = (const int*)d_in[9];
  float* out = (float*)d_out;

  char* ws = (char*)d_ws;
  bf16*  xb    = (bf16*)(ws);                      // 16,777,216 B
  bf16*  wT    = (bf16*)(ws + 16777216);           // 12,582,912 B
  bf16*  woT   = (bf16*)(ws + 29360128);           //  8,388,608 B
  bf16*  qn    = (bf16*)(ws + 37748736);           // 16,777,216 B
  bf16*  kn    = (bf16*)(ws + 54525952);           //  4,194,304 B
  bf16*  vTb   = (bf16*)(ws + 58720256);           //  4,194,304 B
  bf16*  y     = (bf16*)(ws + 62914560);           // 16,777,216 B
  float* gate4 = (float*)(ws + 79691776);          //     65,536 B

  // fused preamble: x cast + W transposes + gate vector, ONE launch
  prep_kernel<<<20480, 256, 0, stream>>>(x, Wq, Wk, Wv, Wo, Wg,
                                         (ushort4*)xb, wT, woT, gate4);
  // fused QKV GEMM + rope/rmsnorm/gate epilogue: 32x24 tiles of 128x128, 768 blocks
  gemm_qkvf<<<768, 512, 0, stream>>>(xb, wT, ve, cosT, sinT, gate4, qn, kn, vTb);
  attn_kernel<<<512, 256, 0, stream>>>(qn, kn, vTb, y, win);
  // Wo: 32x16 tiles of 128x128 -> 512 blocks, 2 blocks/CU; regions 8x8
  gemm_q4<4, 2, float><<<512, 512, 0, stream>>>(y, woT, out, 2048, 2048, 8, 8);
}

// Round 20
// 174.881 us; speedup vs baseline: 1.1580x; 1.1580x over previous
//
#include <hip/hip_runtime.h>
#include <hip/hip_bf16.h>
#include <cstdint>

typedef __hip_bfloat16 bf16;
typedef __attribute__((ext_vector_type(8))) short short8;
typedef __attribute__((ext_vector_type(4))) short short4v;
typedef __attribute__((ext_vector_type(4))) float f32x4;

#define T_   2048
#define CDIM 2048
#define NH   16
#define NKV  4
#define HD   128
// 1/sqrt(128) * log2(e), folded into q at the epilogue so attn scores are exp2-ready
#define QSCALE (0.08838834764831845f * 1.44269504088896340f)

__device__ __forceinline__ void gload_lds16(const void* g, void* l) {
  __builtin_amdgcn_global_load_lds(
      (const __attribute__((address_space(1))) void*)g,
      (__attribute__((address_space(3))) void*)l, 16, 0, 0);
}

template <int G> __device__ __forceinline__ void vm_gate() {
  if constexpr (G == 5)      asm volatile("s_waitcnt vmcnt(5)" ::: "memory");
  else if constexpr (G == 4) asm volatile("s_waitcnt vmcnt(4)" ::: "memory");
  else if constexpr (G == 3) asm volatile("s_waitcnt vmcnt(3)" ::: "memory");
  else                       asm volatile("s_waitcnt vmcnt(0)" ::: "memory");
}

// ---------------- fused preamble: cast x + cast/transpose all W ----------------
__global__ __launch_bounds__(256) void prep_kernel(
    const float* __restrict__ x, const float* __restrict__ Wq,
    const float* __restrict__ Wk, const float* __restrict__ Wv,
    const float* __restrict__ Wo, ushort4* __restrict__ xb,
    bf16* __restrict__ wT, bf16* __restrict__ woT) {
  int b = blockIdx.x;
  if (b < 8192) {
    int i = b * 256 + threadIdx.x;
    float4 v = ((const float4*)x)[i];
    union { bf16 h[4]; ushort4 u; } cv;
    cv.h[0] = __float2bfloat16(v.x);
    cv.h[1] = __float2bfloat16(v.y);
    cv.h[2] = __float2bfloat16(v.z);
    cv.h[3] = __float2bfloat16(v.w);
    xb[i] = cv.u;
    return;
  }
  const float* W; bf16* WT; int N, nbx, idx;
  if (b < 12288)      { W = Wq; WT = wT;                       N = 2048; nbx = 64; idx = b - 8192; }
  else if (b < 13312) { W = Wk; WT = wT + (size_t)2048 * 2048; N = 512;  nbx = 16; idx = b - 12288; }
  else if (b < 14336) { W = Wv; WT = wT + (size_t)2560 * 2048; N = 512;  nbx = 16; idx = b - 13312; }
  else                { W = Wo; WT = woT;                      N = 2048; nbx = 64; idx = b - 14336; }
  __shared__ float tile[32][33];
  const int K = 2048;
  int n0 = (idx % nbx) * 32, k0 = (idx / nbx) * 32;
  int r = threadIdx.x >> 5, c = threadIdx.x & 31;
  for (int i = 0; i < 4; ++i)
    tile[r + i * 8][c] = W[(size_t)(k0 + r + i * 8) * N + n0 + c];
  __syncthreads();
  for (int i = 0; i < 4; ++i)
    WT[(size_t)(n0 + r + i * 8) * K + k0 + c] = __float2bfloat16(tile[c][r + i * 8]);
}

// ---------------- quadrant-phase GEMM, parametric BM (MH m-frags/wave) ----------------
// Session optimum (r18). r9/r11 double-barrier, r14 32x32 shape, r15 attn QK-hoist,
// r19 epilogue fusion: all REFUTED by measurement. MH=4 -> LDS <= 80KB -> 2 blocks/CU
// (m114 cross-block overlap; r17: QKV 56.4->54.6, occ 19->34).
template <int MH, int NF, typename CT>
__global__ __launch_bounds__(512, 2) void gemm_q4(const bf16* __restrict__ A,
                                                  const bf16* __restrict__ BT,
                                                  CT* __restrict__ C,
                                                  int N, int K, int RY, int RX) {
  constexpr int BM = MH * 32;
  constexpr int BN = NF * 64;
  constexpr int MQ = MH / 2;
  constexpr int ALOADS = (MH + 3) / 4;
  constexpr int NB0 = (NF + 1) / 2;
  constexpr int NB1 = NF - NB0;
  constexpr int GATE = NF + ALOADS;
  __shared__ __align__(16) bf16 sA[2][BM * 64];
  __shared__ __align__(16) bf16 sB[2][BN * 64];

  int tid = threadIdx.x;
  int lane = tid & 63, w = tid >> 6;
  int wm = w >> 2, wn = w & 3;
  int lr = lane & 15, lk = lane >> 4;

  int xcd = blockIdx.x & 7, t = blockIdx.x >> 3;
  int by = (xcd >> 1) * RY + t / RX;
  int bx = (xcd & 1) * RX + t % RX;
  int m0 = by * BM, n0 = bx * BN;

  f32x4 acc[MH][NF];
#pragma unroll
  for (int m = 0; m < MH; ++m)
#pragma unroll
    for (int n = 0; n < NF; ++n) acc[m][n] = (f32x4){0.f, 0.f, 0.f, 0.f};

  const bf16* Abase = A + (size_t)m0 * K;
  const bf16* Bbase = BT + (size_t)n0 * K;

  auto stB = [&](int p, int kt) {
    int kb = kt << 6;
#pragma unroll
    for (int i = 0; i < NF; ++i) {
      int c = i * 512 + tid;
      int r = c >> 3, sl = c & 7;
      gload_lds16(Bbase + (size_t)r * K + kb + ((sl ^ (r & 7)) << 3),
                  (char*)(&sB[p][0]) + c * 16);
    }
  };
  auto stA = [&](int p, int kt, int h) {
    int kb = kt << 6;
#pragma unroll
    for (int i = 0; i < ALOADS; ++i) {
      int c = i * 512 + tid;
      int r = (c >> 3) + h * (BM / 2), sl = c & 7;
      gload_lds16(Abase + (size_t)r * K + kb + ((sl ^ (r & 7)) << 3),
                  (char*)(&sA[p][0]) + r * 128 + sl * 16);
    }
  };

  int nk = K >> 6;
  stB(0, 0); stA(0, 0, 0); stA(0, 0, 1);
  stB(1, 1); stA(1, 1, 0);
  vm_gate<GATE>();
  __builtin_amdgcn_s_barrier();

#define READ_AF(DST, QM)                                                   \
  {                                                                        \
    _Pragma("unroll")                                                      \
    for (int mi = 0; mi < MQ; ++mi) {                                      \
      int row = wm * (MH * 16) + (QM) * (MQ * 16) + mi * 16 + lr;          \
      const char* rb = sAb + row * 128;                                    \
      int rx = (row & 7) << 4;                                             \
      DST[mi][0] = *(const short8*)(rb + ((lk * 16) ^ rx));                \
      DST[mi][1] = *(const short8*)(rb + ((64 + lk * 16) ^ rx));           \
    }                                                                      \
  }
#define READ_BF(DST, FBASE, CNT)                                           \
  {                                                                        \
    _Pragma("unroll")                                                      \
    for (int f = 0; f < (CNT); ++f) {                                      \
      int row = wn * (NF * 16) + ((FBASE) + f) * 16 + lr;                  \
      const char* rb = sBb + row * 128;                                    \
      int rx = (row & 7) << 4;                                             \
      DST[f][0] = *(const short8*)(rb + ((lk * 16) ^ rx));                 \
      DST[f][1] = *(const short8*)(rb + ((64 + lk * 16) ^ rx));            \
    }                                                                      \
  }
#define MFMA_Q(AF, BF, QM, FBASE, CNT)                                     \
  __builtin_amdgcn_s_setprio(1);                                           \
  _Pragma("unroll")                                                        \
  for (int kk = 0; kk < 2; ++kk)                                           \
    _Pragma("unroll")                                                      \
    for (int mi = 0; mi < MQ; ++mi)                                        \
      _Pragma("unroll")                                                    \
      for (int f = 0; f < (CNT); ++f)                                      \
        acc[(QM) * MQ + mi][(FBASE) + f] =                                 \
            __builtin_amdgcn_mfma_f32_16x16x32_bf16(                       \
                AF[mi][kk], BF[f][kk], acc[(QM) * MQ + mi][(FBASE) + f],   \
                0, 0, 0);                                                  \
  __builtin_amdgcn_s_setprio(0);
#define RD_SYNC                                                            \
  __builtin_amdgcn_s_barrier();                                            \
  asm volatile("s_waitcnt lgkmcnt(0)" ::: "memory");                       \
  __builtin_amdgcn_sched_barrier(0);

  for (int kt = 0; kt < nk; ++kt) {
    int p = kt & 1;
    const char* sAb = (const char*)(&sA[p][0]);
    const char* sBb = (const char*)(&sB[p][0]);
    short8 af0[MQ][2], af1[MQ][2], bf0[NB0][2], bf1[NB1][2];

    READ_AF(af0, 0);
    READ_BF(bf0, 0, NB0);
    if (kt + 1 < nk) stA(p ^ 1, kt + 1, 1);
    RD_SYNC;
    MFMA_Q(af0, bf0, 0, 0, NB0);
    __builtin_amdgcn_s_barrier();

    READ_BF(bf1, NB0, NB1);
    RD_SYNC;
    MFMA_Q(af0, bf1, 0, NB0, NB1);
    __builtin_amdgcn_s_barrier();

    READ_AF(af1, 1);
    if (kt + 2 < nk) stB(p, kt + 2);
    RD_SYNC;
    MFMA_Q(af1, bf1, 1, NB0, NB1);
    __builtin_amdgcn_s_barrier();

    if (kt + 2 < nk) stA(p, kt + 2, 0);
    MFMA_Q(af1, bf0, 1, 0, NB0);
    if (kt + 2 < nk) vm_gate<GATE>();
    else             vm_gate<0>();
    __builtin_amdgcn_s_barrier();
  }
#undef READ_AF
#undef READ_BF
#undef MFMA_Q
#undef RD_SYNC

#pragma unroll
  for (int m = 0; m < MH; ++m)
#pragma unroll
    for (int n = 0; n < NF; ++n)
#pragma unroll
      for (int jj = 0; jj < 4; ++jj) {
        size_t idx = (size_t)(m0 + wm * (MH * 16) + (m / MQ) * (MQ * 16) +
                              (m % MQ) * 16 + lk * 4 + jj) * N +
                     n0 + wn * (NF * 16) + n * 16 + lr;
        if constexpr (__is_same(CT, float))
          C[idx] = acc[m][n][jj];
        else
          C[idx] = __float2bfloat16(acc[m][n][jj]);
      }
}

// ---------------- epilogue: gate, v-update(+transpose), RoPE + RMSNorm ----------------
__global__ __launch_bounds__(256) void epilogue_kernel(
    const bf16* __restrict__ qkv, const float* __restrict__ x,
    const float* __restrict__ ve, const float* __restrict__ cosT,
    const float* __restrict__ sinT, const float* __restrict__ Wg,
    bf16* __restrict__ qn, bf16* __restrict__ kn, bf16* __restrict__ vT) {
  int row = blockIdx.x;
  int bi = row >> 11, t = row & 2047;
  int tid = threadIdx.x, lane = tid & 63, w = tid >> 6;
  __shared__ float gate[NKV];
  size_t rb = (size_t)row * 3072;

  if (tid < 128) {
    int g = tid >> 5, i = tid & 31;
    float p = x[(size_t)row * CDIM + i] * Wg[i * 4 + g];
    p += __shfl_xor(p, 1);  p += __shfl_xor(p, 2);
    p += __shfl_xor(p, 4);  p += __shfl_xor(p, 8);
    p += __shfl_xor(p, 16);
    if (i == 0) gate[g] = 2.f / (1.f + __expf(-p));
  }
  __syncthreads();

  float cv = cosT[t * 64 + lane];
  float sv = sinT[t * 64 + lane];

  for (int it = 0; it < 4; ++it) {
    int h = it * 4 + w;
    float x1 = __bfloat162float(qkv[rb + h * 128 + lane]);
    float x2 = __bfloat162float(qkv[rb + h * 128 + 64 + lane]);
    float y1 = x1 * cv + x2 * sv;
    float y2 = x2 * cv - x1 * sv;
    float ss = y1 * y1 + y2 * y2;
    ss += __shfl_xor(ss, 1);  ss += __shfl_xor(ss, 2);  ss += __shfl_xor(ss, 4);
    ss += __shfl_xor(ss, 8);  ss += __shfl_xor(ss, 16); ss += __shfl_xor(ss, 32);
    float r = rsqrtf(ss * (1.f / 128.f) + 1e-6f) * QSCALE;
    size_t ob = (size_t)row * (NH * HD) + h * 128;
    qn[ob + lane] = __float2bfloat16(y1 * r);
    qn[ob + 64 + lane] = __float2bfloat16(y2 * r);
  }
  {
    int h = w;
    float x1 = __bfloat162float(qkv[rb + 2048 + h * 128 + lane]);
    float x2 = __bfloat162float(qkv[rb + 2048 + h * 128 + 64 + lane]);
    float y1 = x1 * cv + x2 * sv;
    float y2 = x2 * cv - x1 * sv;
    float ss = y1 * y1 + y2 * y2;
    ss += __shfl_xor(ss, 1);  ss += __shfl_xor(ss, 2);  ss += __shfl_xor(ss, 4);
    ss += __shfl_xor(ss, 8);  ss += __shfl_xor(ss, 16); ss += __shfl_xor(ss, 32);
    float r = rsqrtf(ss * (1.f / 128.f) + 1e-6f);
    size_t ob = (size_t)row * (NKV * HD) + h * 128;
    kn[ob + lane] = __float2bfloat16(y1 * r);
    kn[ob + 64 + lane] = __float2bfloat16(y2 * r);
  }
  for (int e = tid; e < 512; e += 256) {
    int kv = e >> 7, d = e & 127;
    float val = __bfloat162float(qkv[rb + 2560 + e]) + gate[kv] * ve[(size_t)row * 512 + e];
    vT[((size_t)(bi * NKV + kv) * HD + d) * T_ + t] = __float2bfloat16(val);
  }
}

// ---------------- flash attention v7: QBLK=128, double-buffered LDS, 1 barrier/tile --
__global__ __launch_bounds__(256, 2) void attn_kernel(
    const bf16* __restrict__ qn, const bf16* __restrict__ kn,
    const bf16* __restrict__ vT, bf16* __restrict__ y,
    const int* __restrict__ winp) {
  __shared__ __align__(16) bf16 sK[2][64 * 128];
  __shared__ __align__(16) bf16 sV[2][128 * 64];

  int win = *winp;
  int id = blockIdx.x;
  int g  = id & 7;
  int bi = g >> 2, kvh = g & 3;
  int rem = id >> 3;
  int h  = kvh * 4 + (rem & 3);
  int q0 = (rem >> 2) << 7;
  int tid = threadIdx.x;
  int lane = tid & 63, w = tid >> 6;
  int lr = lane & 15, lk = lane >> 4;

  short8 qfA[4], qfB[4];
  {
    const bf16* qrA = qn + (size_t)(bi * T_ + q0 + w * 32 + lr) * (NH * HD) + h * HD;
    const bf16* qrB = qrA + (size_t)16 * (NH * HD);
#pragma unroll
    for (int c = 0; c < 4; ++c) {
      qfA[c] = *(const short8*)(qrA + c * 32 + lk * 8);
      qfB[c] = *(const short8*)(qrB + c * 32 + lk * 8);
    }
  }

  int kge[4], klb[4], vge[4], vlbA[4], vlbB[4];
#pragma unroll
  for (int i = 0; i < 4; ++i) {
    int c = i * 256 + tid;
    int kr = c >> 4, ks = c & 15;
    kge[i] = kr * (NKV * HD) + ks * 8;
    klb[i] = kr * 256 + ((ks ^ (kr & 7)) << 4);
    int vr = c >> 3, vs = c & 7;
    vge[i] = vr * T_ + vs * 8;
    int hh = vs >> 2, m = vs & 3, a = m >> 1;
    int sA = 8 * ((2 * m) & 3) + 4 * a;
    int sB = 8 * ((2 * m + 1) & 3) + 4 * a;
    int tA = 64 * hh + 2 * sA, tB = 64 * hh + 2 * sB;
    vlbA[i] = vr * 128 + (((tA >> 4) ^ (vr & 7)) << 4) + (tA & 15);
    vlbB[i] = vr * 128 + (((tB >> 4) ^ (vr & 7)) << 4) + (tB & 15);
  }
  const bf16* kpane = kn + (size_t)bi * T_ * (NKV * HD) + kvh * HD;
  const bf16* vpane = vT + (size_t)(bi * NKV + kvh) * HD * T_;

  short8 kreg[4], vreg[4];
  auto LOAD = [&](int jtx) {
    const bf16* kb = kpane + (size_t)(jtx << 6) * (NKV * HD);
    const bf16* vb = vpane + (jtx << 6);
#pragma unroll
    for (int i = 0; i < 4; ++i) kreg[i] = *(const short8*)(kb + kge[i]);
#pragma unroll
    for (int i = 0; i < 4; ++i) vreg[i] = *(const short8*)(vb + vge[i]);
  };
  auto WRITE = [&](int b) {
    char* kBuf = (char*)(&sK[b][0]);
    char* vBuf = (char*)(&sV[b][0]);
#pragma unroll
    for (int i = 0; i < 4; ++i) *(short8*)(kBuf + klb[i]) = kreg[i];
#pragma unroll
    for (int i = 0; i < 4; ++i) {
      union { short8 s8; short4v s4[2]; } u;
      u.s8 = vreg[i];
      *(short4v*)(vBuf + vlbA[i]) = u.s4[0];
      *(short4v*)(vBuf + vlbB[i]) = u.s4[1];
    }
  };

  f32x4 o0[8], o1[8];
#pragma unroll
  for (int i = 0; i < 8; ++i) {
    o0[i] = (f32x4){0.f, 0.f, 0.f, 0.f};
    o1[i] = (f32x4){0.f, 0.f, 0.f, 0.f};
  }
  float lp0 = 0.f, lp1 = 0.f;

  int jt0 = q0 >> 6;
  int hi = q0 + 126 + win; if (hi > T_ - 1) hi = T_ - 1;
  int jt1 = hi >> 6;

  LOAD(jt0);
  WRITE(0);
  if (jt0 < jt1) LOAD(jt0 + 1);
  asm volatile("s_waitcnt lgkmcnt(0)\n\ts_barrier" ::: "memory");

  int irow0 = q0 + w * 32 + lr;
  int klo = lk * 4;

  int p = 0;
  for (int jt = jt0; jt <= jt1; ++jt) {
    int j0 = jt << 6;

    if (jt < jt1) {
      WRITE(p ^ 1);
      if (jt + 1 < jt1) LOAD(jt + 2);
    }

    const char* sKb = (const char*)(&sK[p][0]);
    const char* sVb = (const char*)(&sV[p][0]);

    f32x4 s0[4], s1[4];
#pragma unroll
    for (int sub = 0; sub < 4; ++sub) {
      s0[sub] = (f32x4){0.f, 0.f, 0.f, 0.f};
      s1[sub] = (f32x4){0.f, 0.f, 0.f, 0.f};
    }
    __builtin_amdgcn_s_setprio(1);
#pragma unroll
    for (int sub = 0; sub < 4; ++sub) {
      int kr = sub * 16 + lr;
      int rx = (kr & 7) << 4;
      const char* rowb = sKb + kr * 256;
#pragma unroll
      for (int c = 0; c < 4; ++c) {
        short8 kf = *(const short8*)(rowb + ((c * 64 + lk * 16) ^ rx));
        s0[sub] = __builtin_amdgcn_mfma_f32_16x16x32_bf16(kf, qfA[c], s0[sub], 0, 0, 0);
        s1[sub] = __builtin_amdgcn_mfma_f32_16x16x32_bf16(kf, qfB[c], s1[sub], 0, 0, 0);
      }
    }
    __builtin_amdgcn_s_setprio(0);

    bool full = (j0 >= q0 + 128) && (j0 + 64 <= q0 + win);
    int koff0 = j0 - irow0;
    int koff1 = koff0 - 16;

    short8 pA0, pA1, pB0, pB1;
    {
      unsigned pk[8];
#pragma unroll
      for (int sub = 0; sub < 4; ++sub) {
        float p0 = exp2f(s0[sub][0]), p1 = exp2f(s0[sub][1]);
        float p2 = exp2f(s0[sub][2]), p3 = exp2f(s0[sub][3]);
        if (!full) {
          int base = koff0 + sub * 16 + klo;
          p0 = ((unsigned)(base + 0) < (unsigned)win) ? p0 : 0.f;
          p1 = ((unsigned)(base + 1) < (unsigned)win) ? p1 : 0.f;
          p2 = ((unsigned)(base + 2) < (unsigned)win) ? p2 : 0.f;
          p3 = ((unsigned)(base + 3) < (unsigned)win) ? p3 : 0.f;
        }
        lp0 += (p0 + p1) + (p2 + p3);
        asm("v_cvt_pk_bf16_f32 %0, %1, %2" : "=v"(pk[sub * 2])     : "v"(p0), "v"(p1));
        asm("v_cvt_pk_bf16_f32 %0, %1, %2" : "=v"(pk[sub * 2 + 1]) : "v"(p2), "v"(p3));
      }
      union { unsigned u[4]; short8 s8; } c0, c1;
      c0.u[0] = pk[0]; c0.u[1] = pk[1]; c0.u[2] = pk[2]; c0.u[3] = pk[3];
      c1.u[0] = pk[4]; c1.u[1] = pk[5]; c1.u[2] = pk[6]; c1.u[3] = pk[7];
      pA0 = c0.s8; pA1 = c1.s8;
    }
    {
      unsigned pk[8];
#pragma unroll
      for (int sub = 0; sub < 4; ++sub) {
        float p0 = exp2f(s1[sub][0]), p1 = exp2f(s1[sub][1]);
        float p2 = exp2f(s1[sub][2]), p3 = exp2f(s1[sub][3]);
        if (!full) {
          int base = koff1 + sub * 16 + klo;
          p0 = ((unsigned)(base + 0) < (unsigned)win) ? p0 : 0.f;
          p1 = ((unsigned)(base + 1) < (unsigned)win) ? p1 : 0.f;
          p2 = ((unsigned)(base + 2) < (unsigned)win) ? p2 : 0.f;
          p3 = ((unsigned)(base + 3) < (unsigned)win) ? p3 : 0.f;
        }
        lp1 += (p0 + p1) + (p2 + p3);
        asm("v_cvt_pk_bf16_f32 %0, %1, %2" : "=v"(pk[sub * 2])     : "v"(p0), "v"(p1));
        asm("v_cvt_pk_bf16_f32 %0, %1, %2" : "=v"(pk[sub * 2 + 1]) : "v"(p2), "v"(p3));
      }
      union { unsigned u[4]; short8 s8; } c0, c1;
      c0.u[0] = pk[0]; c0.u[1] = pk[1]; c0.u[2] = pk[2]; c0.u[3] = pk[3];
      c1.u[0] = pk[4]; c1.u[1] = pk[5]; c1.u[2] = pk[6]; c1.u[3] = pk[7];
      pB0 = c0.s8; pB1 = c1.s8;
    }

    __builtin_amdgcn_s_setprio(1);
#pragma unroll
    for (int nb = 0; nb < 8; ++nb) {
      int vr = nb * 16 + lr;
      int vrx = (vr & 7) << 4;
      const char* vb = sVb + vr * 128;
      short8 vf0 = *(const short8*)(vb + ((lk * 16) ^ vrx));
      short8 vf1 = *(const short8*)(vb + ((64 + lk * 16) ^ vrx));
      o0[nb] = __builtin_amdgcn_mfma_f32_16x16x32_bf16(pA0, vf0, o0[nb], 0, 0, 0);
      o0[nb] = __builtin_amdgcn_mfma_f32_16x16x32_bf16(pA1, vf1, o0[nb], 0, 0, 0);
      o1[nb] = __builtin_amdgcn_mfma_f32_16x16x32_bf16(pB0, vf0, o1[nb], 0, 0, 0);
      o1[nb] = __builtin_amdgcn_mfma_f32_16x16x32_bf16(pB1, vf1, o1[nb], 0, 0, 0);
    }
    __builtin_amdgcn_s_setprio(0);

    asm volatile("s_waitcnt lgkmcnt(0)\n\ts_barrier" ::: "memory");
    p ^= 1;
  }

  float l0 = lp0, l1 = lp1;
  l0 += __shfl_xor(l0, 16); l0 += __shfl_xor(l0, 32);
  l1 += __shfl_xor(l1, 16); l1 += __shfl_xor(l1, 32);
#pragma unroll
  for (int jj = 0; jj < 4; ++jj) {
    float inv0 = 1.f / __shfl(l0, klo + jj);
    float inv1 = 1.f / __shfl(l1, klo + jj);
    size_t ob0 = (size_t)(bi * T_ + q0 + w * 32 + klo + jj) * (NH * HD) + h * HD;
    size_t ob1 = ob0 + (size_t)16 * (NH * HD);
#pragma unroll
    for (int nb = 0; nb < 8; ++nb) {
      y[ob0 + nb * 16 + lr] = __float2bfloat16(o0[nb][jj] * inv0);
      y[ob1 + nb * 16 + lr] = __float2bfloat16(o1[nb][jj] * inv1);
    }
  }
}

extern "C" void kernel_launch(void* const* d_in, const int* in_sizes, int n_in,
                              void* d_out, int out_size, void* d_ws, size_t ws_size,
                              hipStream_t stream) {
  const float* x    = (const float*)d_in[0];
  const float* ve   = (const float*)d_in[1];
  const float* cosT = (const float*)d_in[2];
  const float* sinT = (const float*)d_in[3];
  const float* Wq   = (const float*)d_in[4];
  const float* Wk   = (const float*)d_in[5];
  const float* Wv   = (const float*)d_in[6];
  const float* Wg   = (const float*)d_in[7];
  const float* Wo   = (const float*)d_in[8];
  const int*   win  = (const int*)d_in[9];
  float* out = (float*)d_out;

  char* ws = (char*)d_ws;
  bf16*  xb   = (bf16*)(ws);
  bf16*  wT   = (bf16*)(ws + 16777216);
  bf16*  woT  = (bf16*)(ws + 29360128);
  bf16*  qkvb = (bf16*)(ws + 37748736);
  bf16*  qn   = (bf16*)(ws + 62914560);
  bf16*  kn   = (bf16*)(ws + 79691776);
  bf16*  vTb  = (bf16*)(ws + 83886080);
  bf16*  y    = qkvb;

  // fused preamble: x cast + Wq/Wk/Wv/Wo cast-transpose in ONE launch
  prep_kernel<<<18432, 256, 0, stream>>>(x, Wq, Wk, Wv, Wo, (ushort4*)xb, wT, woT);

  // QKV: 32x16 tiles of 128x192 -> 512 blocks, 2 blocks/CU (LDS 80KB); regions 8x8
  gemm_q4<4, 3, bf16><<<512, 512, 0, stream>>>(xb, wT, qkvb, 3072, 2048, 8, 8);
  epilogue_kernel<<<4096, 256, 0, stream>>>(qkvb, x, ve, cosT, sinT, Wg, qn, kn, vTb);
  attn_kernel<<<512, 256, 0, stream>>>(qn, kn, vTb, y, win);
  // Wo: 32x16 tiles of 128x128 -> 512 blocks, 2 blocks/CU (LDS 64KB); regions 8x8
  gemm_q4<4, 2, float><<<512, 512, 0, stream>>>(y, woT, out, 2048, 2048, 8, 8);
}